// Round 2
// baseline (1173.765 us; speedup 1.0000x reference)
//
#include <hip/hip_runtime.h>

#define B_SZ 8192
#define IN_SZ 1024
#define G_SZ 100
#define F_SZ 128

using f32x4 = __attribute__((ext_vector_type(4))) float;
using s16x8 = __attribute__((ext_vector_type(8))) short;
typedef __bf16 bf16x8 __attribute__((ext_vector_type(8)));

__device__ __forceinline__ unsigned short f2bf(float f) {
    union { float f; unsigned u; } v; v.f = f;
    unsigned r = v.u + 0x7fffu + ((v.u >> 16) & 1u);
    return (unsigned short)(r >> 16);
}
__device__ __forceinline__ float bf2f(unsigned short h) {
    union { unsigned u; float f; } v; v.u = ((unsigned)h) << 16;
    return v.f;
}

// ---------------------------------------------------------------------------
// Gather: Ag[g][b][f] = bf16(x[b][uf[g*128+f]]).  x rows staged in LDS so the
// random column gather hits LDS, not L2; global reads & writes fully coalesced.
// ---------------------------------------------------------------------------
__global__ __launch_bounds__(256) void k_gather(const float* __restrict__ x,
                                                const int* __restrict__ uf,
                                                unsigned short* __restrict__ Ag) {
    __shared__ __align__(16) unsigned short xrow[16][1032];
    const int t = threadIdx.x;
    const int b0 = blockIdx.x * 16;
    // stage 16 rows of x (f32 -> bf16)
    #pragma unroll
    for (int i = 0; i < 16; ++i) {
        int c4 = t + i * 256;              // 4096 float4 chunks
        int r = c4 >> 8;
        int cc = (c4 & 255) << 2;
        float4 v = *reinterpret_cast<const float4*>(&x[(size_t)(b0 + r) * IN_SZ + cc]);
        ushort4 o; o.x = f2bf(v.x); o.y = f2bf(v.y); o.z = f2bf(v.z); o.w = f2bf(v.w);
        *reinterpret_cast<ushort4*>(&xrow[r][cc]) = o;
    }
    __syncthreads();
    // gather: 100 g * 16 r * 32 chunks(4 feats) = 51200 chunks
    for (int i = 0; i < 200; ++i) {
        int c = t + i * 256;
        int ch = c & 31; int r = (c >> 5) & 15; int g = c >> 9;
        int4 id = *reinterpret_cast<const int4*>(&uf[g * F_SZ + ch * 4]);
        ushort4 o;
        o.x = xrow[r][id.x]; o.y = xrow[r][id.y]; o.z = xrow[r][id.z]; o.w = xrow[r][id.w];
        *reinterpret_cast<ushort4*>(&Ag[(((size_t)g * B_SZ + b0 + r) << 7) + ch * 4]) = o;
    }
}

// ---------------------------------------------------------------------------
// Per-group dense layer, bf16 MFMA 16x16x32 (builtin -> compiler-managed
// hazards).  block = (group g, 128-row M tile), 256 threads = 4 waves.
//   A_lds[row][k] and W_lds[n][k] with 16B-chunk XOR swizzle.
//   BN_IN: apply y = relu(h*sa + sb) while staging A.
//   !IS_LAST: write bf16 H[g][b][n], accumulate BN sums.
//   IS_LAST:  write f32 pred[b][g*50+n], accumulate pred . out_weight per row.
// ---------------------------------------------------------------------------
template<int K_SRC, int N_OUT, int NP, bool BN_IN, bool IS_LAST>
__global__ __launch_bounds__(256) void k_dense(
    const unsigned short* __restrict__ Ain,   // [G][B][K_SRC] bf16
    const float* __restrict__ W,              // [G][K_SRC][N_OUT] f32
    const float* __restrict__ bias,           // [G][N_OUT]
    const float* __restrict__ sa, const float* __restrict__ sb, // [G*K_SRC]
    unsigned short* __restrict__ Hout,        // [G][B][N_OUT] bf16
    float* __restrict__ pred,                 // [B][5000] f32
    float* __restrict__ ssum, float* __restrict__ ssq, // [G*N_OUT]
    const float* __restrict__ ow, float* __restrict__ out_acc)
{
    __shared__ __align__(16) unsigned short A_lds[128 * 128];
    __shared__ __align__(16) unsigned short W_lds[NP * 128];
    __shared__ float ls1[112];
    __shared__ float ls2[112];

    const int t = threadIdx.x;
    const int g = blockIdx.x >> 6;
    const int m0 = (blockIdx.x & 63) << 7;

    if (!IS_LAST && t < NP) { ls1[t] = 0.f; ls2[t] = 0.f; }

    // ---- stage W (transposed to [n][k], zero-padded, swizzled) ----
    constexpr int WI = NP * 128 / 256;
    #pragma unroll
    for (int i = 0; i < WI; ++i) {
        int e = t + i * 256;
        int n = e % NP, k = e / NP;
        float wv = 0.f;
        if (n < N_OUT && k < K_SRC) wv = W[((size_t)g * K_SRC + k) * N_OUT + n];
        W_lds[n * 128 + ((((k >> 3) ^ (n & 7)) << 3) | (k & 7))] = f2bf(wv);
    }

    // ---- stage A (rows coalesced, optional BN+ReLU, zero-pad k>=K_SRC) ----
    const size_t abase = ((size_t)g * B_SZ + m0) * K_SRC;
    #pragma unroll
    for (int i = 0; i < 16; ++i) {
        int c = t + i * 256;
        int ch = c & 31, r = c >> 5;
        int cidx = r * 128 + (((ch >> 1) ^ (r & 7)) << 3) + (ch & 1) * 4; // ushort idx of 4-elem chunk
        if (ch * 4 < K_SRC) {
            ushort4 hv = *reinterpret_cast<const ushort4*>(&Ain[abase + (size_t)r * K_SRC + ch * 4]);
            if (BN_IN) {
                float4 va = *reinterpret_cast<const float4*>(&sa[g * K_SRC + ch * 4]);
                float4 vb = *reinterpret_cast<const float4*>(&sb[g * K_SRC + ch * 4]);
                hv.x = f2bf(fmaxf(0.f, bf2f(hv.x) * va.x + vb.x));
                hv.y = f2bf(fmaxf(0.f, bf2f(hv.y) * va.y + vb.y));
                hv.z = f2bf(fmaxf(0.f, bf2f(hv.z) * va.z + vb.z));
                hv.w = f2bf(fmaxf(0.f, bf2f(hv.w) * va.w + vb.w));
            }
            *reinterpret_cast<ushort4*>(&A_lds[cidx]) = hv;
        } else {
            ushort4 z; z.x = z.y = z.z = z.w = 0;
            *reinterpret_cast<ushort4*>(&A_lds[cidx]) = z;
        }
    }
    __syncthreads();

    // ---- MFMA main loop ----
    const int lane = t & 63, wid = t >> 6;
    const int lrow = lane & 15;
    const int lg = lane >> 4;              // lane group 0..3
    constexpr int NT = NP / 16;
    f32x4 acc[2][NT] = {};

    #pragma unroll
    for (int ks = 0; ks < 4; ++ks) {
        const int cb = ks * 4 + lg;        // 16B chunk index of this lane's k-slice
        const int r0 = wid * 32 + lrow;
        const int r1 = r0 + 16;
        s16x8 a0 = *reinterpret_cast<const s16x8*>(&A_lds[r0 * 128 + ((cb ^ (r0 & 7)) << 3)]);
        s16x8 a1 = *reinterpret_cast<const s16x8*>(&A_lds[r1 * 128 + ((cb ^ (r1 & 7)) << 3)]);
        bf16x8 av0 = __builtin_bit_cast(bf16x8, a0);
        bf16x8 av1 = __builtin_bit_cast(bf16x8, a1);
        #pragma unroll
        for (int nt = 0; nt < NT; ++nt) {
            const int n = nt * 16 + lrow;
            s16x8 b = *reinterpret_cast<const s16x8*>(&W_lds[n * 128 + ((cb ^ (n & 7)) << 3)]);
            bf16x8 bv = __builtin_bit_cast(bf16x8, b);
            acc[0][nt] = __builtin_amdgcn_mfma_f32_16x16x32_bf16(av0, bv, acc[0][nt], 0, 0, 0);
            acc[1][nt] = __builtin_amdgcn_mfma_f32_16x16x32_bf16(av1, bv, acc[1][nt], 0, 0, 0);
        }
    }

    // ---- epilogue ----
    if (!IS_LAST) {
        #pragma unroll
        for (int mi = 0; mi < 2; ++mi) {
            const int rbase = m0 + wid * 32 + mi * 16 + (lg << 2);
            #pragma unroll
            for (int nt = 0; nt < NT; ++nt) {
                const int col = nt * 16 + lrow;
                const bool valid = col < N_OUT;
                const float bv = valid ? bias[g * N_OUT + col] : 0.f;
                float s1 = 0.f, s2 = 0.f;
                #pragma unroll
                for (int r = 0; r < 4; ++r) {
                    float v = acc[mi][nt][r] + bv;
                    unsigned short hb = f2bf(v);
                    float vq = bf2f(hb);
                    s1 += vq; s2 += vq * vq;
                    if (valid)
                        Hout[((size_t)g * B_SZ + rbase + r) * N_OUT + col] = hb;
                }
                s1 += __shfl_xor(s1, 16); s1 += __shfl_xor(s1, 32);
                s2 += __shfl_xor(s2, 16); s2 += __shfl_xor(s2, 32);
                if (valid && lg == 0) {
                    atomicAdd(&ls1[col], s1);
                    atomicAdd(&ls2[col], s2);
                }
            }
        }
        __syncthreads();
        if (t < N_OUT) {
            atomicAdd(&ssum[g * N_OUT + t], ls1[t]);
            atomicAdd(&ssq[g * N_OUT + t], ls2[t]);
        }
    } else {
        #pragma unroll
        for (int mi = 0; mi < 2; ++mi) {
            const int rbase = m0 + wid * 32 + mi * 16 + (lg << 2);
            float dp0 = 0.f, dp1 = 0.f, dp2 = 0.f, dp3 = 0.f;
            #pragma unroll
            for (int nt = 0; nt < NT; ++nt) {
                const int col = nt * 16 + lrow;
                const bool valid = col < N_OUT;
                const float bv = valid ? bias[g * N_OUT + col] : 0.f;
                const float wv = valid ? ow[g * N_OUT + col] : 0.f;
                #pragma unroll
                for (int r = 0; r < 4; ++r) {
                    float v = acc[mi][nt][r] + bv;
                    if (valid) {
                        pred[(size_t)(rbase + r) * 5000 + g * N_OUT + col] = v;
                        if (r == 0) dp0 += v * wv;
                        if (r == 1) dp1 += v * wv;
                        if (r == 2) dp2 += v * wv;
                        if (r == 3) dp3 += v * wv;
                    }
                }
            }
            float dp[4] = {dp0, dp1, dp2, dp3};
            #pragma unroll
            for (int r = 0; r < 4; ++r) {
                float d = dp[r];
                d += __shfl_xor(d, 1); d += __shfl_xor(d, 2);
                d += __shfl_xor(d, 4); d += __shfl_xor(d, 8);
                if (lrow == 0) atomicAdd(&out_acc[rbase + r], d);
            }
        }
    }
}

__global__ __launch_bounds__(256) void k_bnfin(const float* __restrict__ ssum,
                                               const float* __restrict__ ssq,
                                               const float* __restrict__ gamma,
                                               const float* __restrict__ beta,
                                               float* __restrict__ sa,
                                               float* __restrict__ sb, int n) {
    int c = blockIdx.x * 256 + threadIdx.x;
    if (c < n) {
        float mean = ssum[c] * (1.f / 8192.f);
        float var = ssq[c] * (1.f / 8192.f) - mean * mean;
        float s = rsqrtf(var + 1e-5f) * gamma[c];
        sa[c] = s;
        sb[c] = beta[c] - mean * s;
    }
}

__global__ __launch_bounds__(256) void k_sig(const float* __restrict__ out_acc,
                                             const float* __restrict__ ob,
                                             float* __restrict__ out) {
    int b = blockIdx.x * 256 + threadIdx.x;
    if (b < B_SZ) {
        float v = ob[0] + out_acc[b];
        out[b] = 1.f / (1.f + expf(-v));
    }
}

extern "C" void kernel_launch(void* const* d_in, const int* in_sizes, int n_in,
                              void* d_out, int out_size, void* d_ws, size_t ws_size,
                              hipStream_t stream) {
    const float* x      = (const float*)d_in[0];
    const int*   uf     = (const int*)d_in[1];
    const float* w0     = (const float*)d_in[2];
    const float* b0     = (const float*)d_in[3];
    const float* w1     = (const float*)d_in[4];
    const float* b1     = (const float*)d_in[5];
    const float* w2     = (const float*)d_in[6];
    const float* b2     = (const float*)d_in[7];
    const float* gamma0 = (const float*)d_in[8];
    const float* beta0  = (const float*)d_in[9];
    const float* gamma1 = (const float*)d_in[10];
    const float* beta1  = (const float*)d_in[11];
    const float* ow     = (const float*)d_in[12];
    const float* ob     = (const float*)d_in[13];

    char* ws = (char*)d_ws;
    const size_t AG_BYTES = (size_t)G_SZ * B_SZ * 128 * 2;  // 209,715,200
    unsigned short* Ag = (unsigned short*)ws;
    unsigned short* h1 = Ag;  // h1 aliases Ag (Ag dead after dense0)
    float* stat = (float*)(ws + AG_BYTES);
    float* sum0    = stat;            // 10000
    float* ssq0    = stat + 10000;
    float* sum1    = stat + 20000;
    float* ssq1    = stat + 30000;
    float* out_acc = stat + 40000;    // 8192
    float* sa0     = stat + 48192;
    float* sb0     = stat + 58192;
    float* sa1     = stat + 68192;
    float* sb1     = stat + 78192;

    // h0 lives in d_out's pred region (exactly 8192*5000 floats), dead before
    // dense2 overwrites that region with pred.
    unsigned short* h0 = (unsigned short*)((float*)d_out + B_SZ);
    float* pred = (float*)d_out + B_SZ;
    float* sig  = (float*)d_out;

    // zero accumulators (sum0..ssq1 + out_acc contiguous = 48192 floats)
    hipMemsetAsync(stat, 0, 48192 * sizeof(float), stream);

    k_gather<<<B_SZ / 16, 256, 0, stream>>>(x, uf, Ag);

    k_dense<128, 100, 112, false, false><<<6400, 256, 0, stream>>>(
        Ag, w0, b0, nullptr, nullptr, h0, nullptr, sum0, ssq0, nullptr, nullptr);
    k_bnfin<<<40, 256, 0, stream>>>(sum0, ssq0, gamma0, beta0, sa0, sb0, 10000);

    k_dense<100, 100, 112, true, false><<<6400, 256, 0, stream>>>(
        h0, w1, b1, sa0, sb0, h1, nullptr, sum1, ssq1, nullptr, nullptr);
    k_bnfin<<<40, 256, 0, stream>>>(sum1, ssq1, gamma1, beta1, sa1, sb1, 10000);

    k_dense<100, 50, 64, true, true><<<6400, 256, 0, stream>>>(
        h1, w2, b2, sa1, sb1, nullptr, pred, nullptr, nullptr, ow, out_acc);

    k_sig<<<32, 256, 0, stream>>>(out_acc, ob, sig);
}

// Round 3
// 510.903 us; speedup vs baseline: 2.2974x; 2.2974x over previous
//
#include <hip/hip_runtime.h>

#define B_SZ 8192
#define IN_SZ 1024
#define G_SZ 100
#define F_SZ 128

using f32x4 = __attribute__((ext_vector_type(4))) float;
using s16x8 = __attribute__((ext_vector_type(8))) short;
typedef __bf16 bf16x8 __attribute__((ext_vector_type(8)));

__device__ __forceinline__ unsigned short f2bf(float f) {
    union { float f; unsigned u; } v; v.f = f;
    unsigned r = v.u + 0x7fffu + ((v.u >> 16) & 1u);
    return (unsigned short)(r >> 16);
}
__device__ __forceinline__ float bf2f(unsigned short h) {
    union { unsigned u; float f; } v; v.u = ((unsigned)h) << 16;
    return v.f;
}

// ---------------------------------------------------------------------------
// Gather: Ag[g][b][f] = bf16(x[b][uf[g*128+f]]).
// ---------------------------------------------------------------------------
__global__ __launch_bounds__(256) void k_gather(const float* __restrict__ x,
                                                const int* __restrict__ uf,
                                                unsigned short* __restrict__ Ag) {
    __shared__ __align__(16) unsigned short xrow[16][1032];
    const int t = threadIdx.x;
    const int b0 = blockIdx.x * 16;
    #pragma unroll
    for (int i = 0; i < 16; ++i) {
        int c4 = t + i * 256;
        int r = c4 >> 8;
        int cc = (c4 & 255) << 2;
        float4 v = *reinterpret_cast<const float4*>(&x[(size_t)(b0 + r) * IN_SZ + cc]);
        ushort4 o; o.x = f2bf(v.x); o.y = f2bf(v.y); o.z = f2bf(v.z); o.w = f2bf(v.w);
        *reinterpret_cast<ushort4*>(&xrow[r][cc]) = o;
    }
    __syncthreads();
    for (int i = 0; i < 200; ++i) {
        int c = t + i * 256;
        int ch = c & 31; int r = (c >> 5) & 15; int g = c >> 9;
        int4 id = *reinterpret_cast<const int4*>(&uf[g * F_SZ + ch * 4]);
        ushort4 o;
        o.x = xrow[r][id.x]; o.y = xrow[r][id.y]; o.z = xrow[r][id.z]; o.w = xrow[r][id.w];
        *reinterpret_cast<ushort4*>(&Ag[(((size_t)g * B_SZ + b0 + r) << 7) + ch * 4]) = o;
    }
}

// ---------------------------------------------------------------------------
// Per-group dense, bf16 MFMA 16x16x32.
//  - A: loaded DIRECTLY from global into MFMA fragments (no LDS, coalesced at
//    64B/row granularity). BN+ReLU applied per-fragment in registers.
//  - W: staged once per block into LDS in exact fragment order
//    Wf[ks][nt][lane] (16B entries) -> conflict-free b128 write & read.
//    Zero-padded to K=128 / NT*16 cols, so pad-k products are exactly 0.
//  - K_SRC=100: rows are 8B-aligned -> paired short4 loads; k=96..99 handled
//    as a masked tail fragment (no OOB reads).
// ---------------------------------------------------------------------------
template<int K_SRC, int N_OUT, int NT, bool BN_IN, bool IS_LAST>
__global__ __launch_bounds__(256) void k_dense(
    const unsigned short* __restrict__ Ain,   // [G][B][K_SRC] bf16
    const float* __restrict__ W,              // [G][K_SRC][N_OUT] f32
    const float* __restrict__ bias,           // [G][N_OUT]
    const float* __restrict__ sa, const float* __restrict__ sb, // [G*K_SRC]
    unsigned short* __restrict__ Hout,        // [G][B][N_OUT] bf16
    float* __restrict__ pred,                 // [B][5000] f32
    float* __restrict__ ssum, float* __restrict__ ssq, // [G*N_OUT]
    const float* __restrict__ ow, float* __restrict__ out_acc)
{
    constexpr int NKS = 4;                    // K padded to 128
    constexpr int ENT = NKS * NT * 64;        // fragment entries
    __shared__ __align__(16) unsigned short Wf[ENT * 8];
    __shared__ float ls1[NT * 16];
    __shared__ float ls2[NT * 16];

    const int t = threadIdx.x;
    const int g = blockIdx.x >> 6;
    const int m0 = (blockIdx.x & 63) << 7;
    const int lane = t & 63, wid = t >> 6;
    const int lr = lane & 15, lg = lane >> 4;

    if (!IS_LAST && t < NT * 16) { ls1[t] = 0.f; ls2[t] = 0.f; }

    // ---- stage W in fragment order ----
    #pragma unroll
    for (int i = 0; i < ENT / 256; ++i) {
        int e = t + i * 256;
        int el = e & 63, grp = e >> 6;
        int ks = grp / NT, nt = grp % NT;
        int n = nt * 16 + (el & 15);
        int kb = ks * 32 + (el >> 4) * 8;
        s16x8 v;
        #pragma unroll
        for (int j = 0; j < 8; ++j) {
            int k = kb + j;
            float wv = (k < K_SRC && n < N_OUT) ? W[((size_t)g * K_SRC + k) * N_OUT + n] : 0.f;
            v[j] = (short)f2bf(wv);
        }
        *reinterpret_cast<s16x8*>(&Wf[e * 8]) = v;
    }
    __syncthreads();

    const unsigned short* arow0 = Ain + ((size_t)g * B_SZ + m0 + wid * 32 + lr) * K_SRC;
    const unsigned short* arow1 = arow0 + (size_t)16 * K_SRC;

    f32x4 acc[2][NT] = {};
    constexpr int NKS_FULL = K_SRC / 32;

    #pragma unroll
    for (int ks = 0; ks < NKS_FULL; ++ks) {
        const int kb = ks * 32 + lg * 8;
        s16x8 a0, a1;
        if constexpr (K_SRC % 64 == 0) {
            a0 = *reinterpret_cast<const s16x8*>(arow0 + kb);
            a1 = *reinterpret_cast<const s16x8*>(arow1 + kb);
        } else {
            reinterpret_cast<short4*>(&a0)[0] = *reinterpret_cast<const short4*>(arow0 + kb);
            reinterpret_cast<short4*>(&a0)[1] = *reinterpret_cast<const short4*>(arow0 + kb + 4);
            reinterpret_cast<short4*>(&a1)[0] = *reinterpret_cast<const short4*>(arow1 + kb);
            reinterpret_cast<short4*>(&a1)[1] = *reinterpret_cast<const short4*>(arow1 + kb + 4);
        }
        if constexpr (BN_IN) {
            float4 S0 = *reinterpret_cast<const float4*>(&sa[g * K_SRC + kb]);
            float4 S1 = *reinterpret_cast<const float4*>(&sa[g * K_SRC + kb + 4]);
            float4 O0 = *reinterpret_cast<const float4*>(&sb[g * K_SRC + kb]);
            float4 O1 = *reinterpret_cast<const float4*>(&sb[g * K_SRC + kb + 4]);
            #define APP(vv, idx, s, o) { float f_ = bf2f((unsigned short)vv[idx]) * (s) + (o); \
                                         vv[idx] = (short)f2bf(fmaxf(f_, 0.f)); }
            APP(a0,0,S0.x,O0.x) APP(a0,1,S0.y,O0.y) APP(a0,2,S0.z,O0.z) APP(a0,3,S0.w,O0.w)
            APP(a0,4,S1.x,O1.x) APP(a0,5,S1.y,O1.y) APP(a0,6,S1.z,O1.z) APP(a0,7,S1.w,O1.w)
            APP(a1,0,S0.x,O0.x) APP(a1,1,S0.y,O0.y) APP(a1,2,S0.z,O0.z) APP(a1,3,S0.w,O0.w)
            APP(a1,4,S1.x,O1.x) APP(a1,5,S1.y,O1.y) APP(a1,6,S1.z,O1.z) APP(a1,7,S1.w,O1.w)
        }
        bf16x8 av0 = __builtin_bit_cast(bf16x8, a0);
        bf16x8 av1 = __builtin_bit_cast(bf16x8, a1);
        #pragma unroll
        for (int nt = 0; nt < NT; ++nt) {
            s16x8 b = *reinterpret_cast<const s16x8*>(&Wf[((ks * NT + nt) * 64 + lane) * 8]);
            bf16x8 bv = __builtin_bit_cast(bf16x8, b);
            acc[0][nt] = __builtin_amdgcn_mfma_f32_16x16x32_bf16(av0, bv, acc[0][nt], 0, 0, 0);
            acc[1][nt] = __builtin_amdgcn_mfma_f32_16x16x32_bf16(av1, bv, acc[1][nt], 0, 0, 0);
        }
    }

    if constexpr (K_SRC % 32 != 0) {          // masked tail: k = 96..99
        constexpr int kb0 = NKS_FULL * 32;
        s16x8 a0 = {}, a1 = {};
        if (lg == 0) {
            reinterpret_cast<short4*>(&a0)[0] = *reinterpret_cast<const short4*>(arow0 + kb0);
            reinterpret_cast<short4*>(&a1)[0] = *reinterpret_cast<const short4*>(arow1 + kb0);
            if constexpr (BN_IN) {
                float4 S0 = *reinterpret_cast<const float4*>(&sa[g * K_SRC + kb0]);
                float4 O0 = *reinterpret_cast<const float4*>(&sb[g * K_SRC + kb0]);
                APP(a0,0,S0.x,O0.x) APP(a0,1,S0.y,O0.y) APP(a0,2,S0.z,O0.z) APP(a0,3,S0.w,O0.w)
                APP(a1,0,S0.x,O0.x) APP(a1,1,S0.y,O0.y) APP(a1,2,S0.z,O0.z) APP(a1,3,S0.w,O0.w)
            }
        }
        bf16x8 av0 = __builtin_bit_cast(bf16x8, a0);
        bf16x8 av1 = __builtin_bit_cast(bf16x8, a1);
        #pragma unroll
        for (int nt = 0; nt < NT; ++nt) {
            s16x8 b = *reinterpret_cast<const s16x8*>(&Wf[((NKS_FULL * NT + nt) * 64 + lane) * 8]);
            bf16x8 bv = __builtin_bit_cast(bf16x8, b);
            acc[0][nt] = __builtin_amdgcn_mfma_f32_16x16x32_bf16(av0, bv, acc[0][nt], 0, 0, 0);
            acc[1][nt] = __builtin_amdgcn_mfma_f32_16x16x32_bf16(av1, bv, acc[1][nt], 0, 0, 0);
        }
    }

    // ---- epilogue ----
    if (!IS_LAST) {
        #pragma unroll
        for (int mi = 0; mi < 2; ++mi) {
            const int rbase = m0 + wid * 32 + mi * 16 + (lg << 2);
            #pragma unroll
            for (int nt = 0; nt < NT; ++nt) {
                const int col = nt * 16 + lr;
                const bool valid = col < N_OUT;
                const float bv = valid ? bias[g * N_OUT + col] : 0.f;
                float s1 = 0.f, s2 = 0.f;
                #pragma unroll
                for (int r = 0; r < 4; ++r) {
                    float v = acc[mi][nt][r] + bv;
                    unsigned short hb = f2bf(v);
                    float vq = bf2f(hb);
                    s1 += vq; s2 += vq * vq;
                    if (valid)
                        Hout[((size_t)g * B_SZ + rbase + r) * N_OUT + col] = hb;
                }
                s1 += __shfl_xor(s1, 16); s1 += __shfl_xor(s1, 32);
                s2 += __shfl_xor(s2, 16); s2 += __shfl_xor(s2, 32);
                if (valid && lg == 0) {
                    atomicAdd(&ls1[col], s1);
                    atomicAdd(&ls2[col], s2);
                }
            }
        }
        __syncthreads();
        if (t < N_OUT) {
            atomicAdd(&ssum[g * N_OUT + t], ls1[t]);
            atomicAdd(&ssq[g * N_OUT + t], ls2[t]);
        }
    } else {
        #pragma unroll
        for (int mi = 0; mi < 2; ++mi) {
            const int rbase = m0 + wid * 32 + mi * 16 + (lg << 2);
            float dp0 = 0.f, dp1 = 0.f, dp2 = 0.f, dp3 = 0.f;
            #pragma unroll
            for (int nt = 0; nt < NT; ++nt) {
                const int col = nt * 16 + lr;
                const bool valid = col < N_OUT;
                const float bv = valid ? bias[g * N_OUT + col] : 0.f;
                const float wv = valid ? ow[g * N_OUT + col] : 0.f;
                #pragma unroll
                for (int r = 0; r < 4; ++r) {
                    float v = acc[mi][nt][r] + bv;
                    if (valid) {
                        pred[(size_t)(rbase + r) * 5000 + g * N_OUT + col] = v;
                        if (r == 0) dp0 += v * wv;
                        if (r == 1) dp1 += v * wv;
                        if (r == 2) dp2 += v * wv;
                        if (r == 3) dp3 += v * wv;
                    }
                }
            }
            float dp[4] = {dp0, dp1, dp2, dp3};
            #pragma unroll
            for (int r = 0; r < 4; ++r) {
                float d = dp[r];
                d += __shfl_xor(d, 1); d += __shfl_xor(d, 2);
                d += __shfl_xor(d, 4); d += __shfl_xor(d, 8);
                if (lr == 0) atomicAdd(&out_acc[rbase + r], d);
            }
        }
    }
}

__global__ __launch_bounds__(256) void k_bnfin(const float* __restrict__ ssum,
                                               const float* __restrict__ ssq,
                                               const float* __restrict__ gamma,
                                               const float* __restrict__ beta,
                                               float* __restrict__ sa,
                                               float* __restrict__ sb, int n) {
    int c = blockIdx.x * 256 + threadIdx.x;
    if (c < n) {
        float mean = ssum[c] * (1.f / 8192.f);
        float var = ssq[c] * (1.f / 8192.f) - mean * mean;
        float s = rsqrtf(var + 1e-5f) * gamma[c];
        sa[c] = s;
        sb[c] = beta[c] - mean * s;
    }
}

__global__ __launch_bounds__(256) void k_sig(const float* __restrict__ out_acc,
                                             const float* __restrict__ ob,
                                             float* __restrict__ out) {
    int b = blockIdx.x * 256 + threadIdx.x;
    if (b < B_SZ) {
        float v = ob[0] + out_acc[b];
        out[b] = 1.f / (1.f + expf(-v));
    }
}

extern "C" void kernel_launch(void* const* d_in, const int* in_sizes, int n_in,
                              void* d_out, int out_size, void* d_ws, size_t ws_size,
                              hipStream_t stream) {
    const float* x      = (const float*)d_in[0];
    const int*   uf     = (const int*)d_in[1];
    const float* w0     = (const float*)d_in[2];
    const float* b0     = (const float*)d_in[3];
    const float* w1     = (const float*)d_in[4];
    const float* b1     = (const float*)d_in[5];
    const float* w2     = (const float*)d_in[6];
    const float* b2     = (const float*)d_in[7];
    const float* gamma0 = (const float*)d_in[8];
    const float* beta0  = (const float*)d_in[9];
    const float* gamma1 = (const float*)d_in[10];
    const float* beta1  = (const float*)d_in[11];
    const float* ow     = (const float*)d_in[12];
    const float* ob     = (const float*)d_in[13];

    char* ws = (char*)d_ws;
    const size_t AG_BYTES = (size_t)G_SZ * B_SZ * 128 * 2;  // 209,715,200
    unsigned short* Ag = (unsigned short*)ws;
    unsigned short* h1 = Ag;  // h1 aliases Ag (Ag dead after dense0)
    float* stat = (float*)(ws + AG_BYTES);
    float* sum0    = stat;            // 10000
    float* ssq0    = stat + 10000;
    float* sum1    = stat + 20000;
    float* ssq1    = stat + 30000;
    float* out_acc = stat + 40000;    // 8192
    float* sa0     = stat + 48192;
    float* sb0     = stat + 58192;
    float* sa1     = stat + 68192;
    float* sb1     = stat + 78192;

    unsigned short* h0 = (unsigned short*)((float*)d_out + B_SZ);
    float* pred = (float*)d_out + B_SZ;
    float* sig  = (float*)d_out;

    hipMemsetAsync(stat, 0, 48192 * sizeof(float), stream);

    k_gather<<<B_SZ / 16, 256, 0, stream>>>(x, uf, Ag);

    k_dense<128, 100, 7, false, false><<<6400, 256, 0, stream>>>(
        Ag, w0, b0, nullptr, nullptr, h0, nullptr, sum0, ssq0, nullptr, nullptr);
    k_bnfin<<<40, 256, 0, stream>>>(sum0, ssq0, gamma0, beta0, sa0, sb0, 10000);

    k_dense<100, 100, 7, true, false><<<6400, 256, 0, stream>>>(
        h0, w1, b1, sa0, sb0, h1, nullptr, sum1, ssq1, nullptr, nullptr);
    k_bnfin<<<40, 256, 0, stream>>>(sum1, ssq1, gamma1, beta1, sa1, sb1, 10000);

    k_dense<100, 50, 4, true, true><<<6400, 256, 0, stream>>>(
        h1, w2, b2, sa1, sb1, nullptr, pred, nullptr, nullptr, ow, out_acc);

    k_sig<<<32, 256, 0, stream>>>(out_acc, ob, sig);
}